// Round 2
// baseline (167.354 us; speedup 1.0000x reference)
//
#include <hip/hip_runtime.h>
#include <math.h>

// CapsuleLayer: u = x@W via split-precision f16 MFMA (xh@Wh + xl@Wh + xh@Wl),
// 32x32x16. R12: occupancy attack (R10/R11 post-mortem: B-distance null; true
// limiter is 2 waves/SIMD with ~75% per-wave stall -> matrix pipe 25%):
//  - A tile now staged as RAW FP32 via global_load_lds width=16 (same LDS
//    bytes as f16 hi/lo: 4 B/elem). hi/lo split done in registers per kt
//    (24 VALU/kt, hidden under 408cy MFMA issue). Kills sv regs + staging
//    cvt pass + x-load->STAGE vmcnt waits.
//  - Source-side XOR chunk swizzle (c_src = c_phys ^ ((row>>1)&3)), linear
//    LDS dest (rule: both-sides-or-neither with global_load_lds). Frag
//    ds_read_b128 conflict-free: every 8 consecutive lanes cover all 8
//    bank-groups (checked for q=0/q=1, both chunks).
//  - 512-thr blocks (8 waves): wave w owns rows (w>>2)*32..+31, cols
//    (w&3)*128..+127 -> acc[4] = 64 AGPR. ~115 regs total ->
//    __launch_bounds__(512,4) = 2 blocks/CU = 16 waves/CU (2x occupancy).
//  - B: register ping-pong prefetch (R10 scheme; R11 proved distance null).
// Proven invariants: never runtime-index acc[] (R6), lane-bit-5 cross only
// via bpermute (R5), C/D layout row=(reg&3)+8*(reg>>2)+4*q col=ln, routing
// math byte-identical.
//
// x: [32768,512] fp32  W: [512,512] fp32  v: [32768,32] fp32
// prep_w: W[k][n] -> Whl tiled [kt][n][{h,l}][k%16] f16 in d_ws (1 MB).

#define BATCH   32768
#define KDIM    512
#define NDIM    512
#define OUT_DIM 32
#define EPS_F   1e-8f
#define NKT     32            // K tiles of 16
#define KPS     8             // kt per superblock
#define NSB     4             // superblocks

typedef _Float16 half8  __attribute__((ext_vector_type(8)));
typedef float   floatx4 __attribute__((ext_vector_type(4)));
typedef float  floatx16 __attribute__((ext_vector_type(16)));

// ---- cross-lane helpers (R7, proven) ----
template <int CTRL>
__device__ __forceinline__ float dpp_mov(float x) {
    return __int_as_float(__builtin_amdgcn_mov_dpp(__float_as_int(x), CTRL, 0xF, 0xF, true));
}
template <int XMASK>   // XMASK <= 31: ds_swizzle BitMode xor (within 32-lane group)
__device__ __forceinline__ float swz_xor(float x) {
    return __int_as_float(__builtin_amdgcn_ds_swizzle(__float_as_int(x), (XMASK << 10) | 31));
}
#define ROR4  0x124
#define ROR8  0x128
#define QXOR1 0xB1
#define QXOR2 0x4E

__device__ __forceinline__ float cap_sum(float x) {
    x += dpp_mov<ROR4>(x);
    x += dpp_mov<ROR8>(x);
    x += swz_xor<16>(x);
    x += __shfl_xor(x, 32);          // lane bit 5: bpermute only
    return x;
}
__device__ __forceinline__ float cap_max(float x) {
    x = fmaxf(x, dpp_mov<ROR4>(x));
    x = fmaxf(x, dpp_mov<ROR8>(x));
    x = fmaxf(x, swz_xor<16>(x));
    x = fmaxf(x, __shfl_xor(x, 32));
    return x;
}
__device__ __forceinline__ float dg_sum(float x) {
    x += dpp_mov<QXOR1>(x);
    x += dpp_mov<QXOR2>(x);
    return x;
}

#define GLL16(gp, lp)                                                   \
    __builtin_amdgcn_global_load_lds(                                   \
        (const __attribute__((address_space(1))) void*)(gp),            \
        (__attribute__((address_space(3))) void*)(lp), 16, 0, 0)

// ---- prep: W[k][n] fp32 -> Whl [kt][n][{h(16B),l(16B)} per q] f16 ----
// Layout in halfs: off = kt*16384 + n*32 + (k&15); h at off, l at off+16.
__global__ void prep_w(const float* __restrict__ W, _Float16* __restrict__ Whl) {
    __shared__ float tile[32][33];
    const int tx = threadIdx.x, ty = threadIdx.y;      // block (32, 8)
    const int n0 = blockIdx.x * 32, k0 = blockIdx.y * 32;
#pragma unroll
    for (int i = 0; i < 4; ++i)
        tile[ty + 8 * i][tx] = W[(size_t)(k0 + ty + 8 * i) * NDIM + n0 + tx];
    __syncthreads();
#pragma unroll
    for (int i = 0; i < 4; ++i) {
        const int k = k0 + tx, n = n0 + ty + 8 * i;
        const float v = tile[tx][ty + 8 * i];          // = W[k][n]
        const _Float16 h = (_Float16)v;
        const _Float16 l = (_Float16)(v - (float)h);
        const size_t off = (size_t)(k >> 4) * (NDIM * 32) + (size_t)n * 32 + (k & 15);
        Whl[off]      = h;
        Whl[off + 16] = l;
    }
}

__global__ __launch_bounds__(512, 4)
void capsule_mfma(const float* __restrict__ x, const _Float16* __restrict__ Whl,
                  float* __restrict__ out) {
    // A fp32 dbuf: [2][kt'(8)][row(64)][chunk(4)][4 floats] = 2x32KB = 64 KB,
    // unioned with u_lds[32][520] fp32 (66.56 KB).
    __shared__ __align__(16) char smem[66560];
    float (*u_lds)[520] = (float (*)[520])smem;

    const int tid  = threadIdx.x;
    const int w    = tid >> 6;          // wave 0..7
    const int lane = tid & 63;
    const int ln = lane & 31, q = lane >> 5;
    const int mf   = w >> 2;            // m-half: rows mf*32..+31 (uniform/wave)
    const int rowBlk = blockIdx.x * 64;
    const int C0 = (w & 3) * 128;       // col strip

    floatx16 acc[4];
#pragma unroll
    for (int nt = 0; nt < 4; ++nt)
#pragma unroll
        for (int i = 0; i < 16; ++i) acc[nt][i] = 0.f;

    // ---- A staging (global_load_lds): thread t -> dest byte t*16 + i*8192.
    // dest16 = t + 512*i decodes as (kt'=d>>8, row=(d>>2)&63, c_phys=d&3).
    // Source supplies logical chunk c = c_phys ^ ((row>>1)&3)  (inverse-swz).
    const int srow = (tid >> 2) & 63;
    const int sktb = tid >> 8;               // 0..1
    const int scp  = tid & 3;                // physical chunk
    const int ssw  = (srow >> 1) & 3;
    const float* gsrc0 = x + (size_t)(rowBlk + srow) * KDIM
                           + sktb * 16 + (scp ^ ssw) * 4;

    // ---- A frag read offsets (bytes within a kt-slice): row r = mf*32+ln,
    // logical chunks 2q / 2q+1 live at physical (2q)^asw / (2q+1)^asw.
    const int ar   = mf * 32 + ln;
    const int asw  = (ar >> 1) & 3;
    const int aoff0 = ar * 64 + (((2 * q)     ^ asw) * 16);
    const int aoff1 = ar * 64 + (((2 * q + 1) ^ asw) * 16);

    // ---- B lane offset (halfs) within (kt,nt) block of interleaved Whl ----
    const int lane_off = (C0 + ln) * 32 + q * 8;   // + nt*1024 + kt*16384

    // ---- prologue: issue slice 0 -> buf0; preload B(0,0) into slot 0 ----
#pragma unroll
    for (int i = 0; i < 4; ++i)
        GLL16(gsrc0 + 32 * i, smem + tid * 16 + i * 8192);
    half8 bh[2], bl[2];
    {
        const _Float16* bp = Whl + lane_off;
        bh[0] = *(const half8*)bp;
        bl[0] = *(const half8*)(bp + 16);
    }

#define COMPUTE_KK(kk)                                                          \
    {                                                                           \
        const int kt = s * KPS + (kk);                                          \
        const char* ab = smem + abuf + (kk) * 4096;                             \
        const floatx4 af0 = *(const floatx4*)(ab + aoff0);                      \
        const floatx4 af1 = *(const floatx4*)(ab + aoff1);                      \
        half8 ah, al;                                                           \
        _Pragma("unroll")                                                       \
        for (int j = 0; j < 4; ++j) {                                           \
            const float f0 = af0[j], f1 = af1[j];                               \
            const _Float16 h0 = (_Float16)f0, h1 = (_Float16)f1;                \
            ah[j] = h0;  ah[j + 4] = h1;                                        \
            al[j]     = (_Float16)(f0 - (float)h0);                            \
            al[j + 4] = (_Float16)(f1 - (float)h1);                            \
        }                                                                       \
        const int ktn = (kt + 1 < NKT) ? kt + 1 : kt;                           \
        const _Float16* bkt_cur = Whl + (size_t)kt  * 16384 + lane_off;         \
        const _Float16* bkt_nxt = Whl + (size_t)ktn * 16384 + lane_off;         \
        _Pragma("unroll")                                                       \
        for (int nt = 0; nt < 4; ++nt) {                                        \
            const int cu = nt & 1, nx = cu ^ 1;                                 \
            const _Float16* bn = (nt < 3) ? (bkt_cur + (nt + 1) * 1024)         \
                                          : bkt_nxt;                            \
            bh[nx] = *(const half8*)bn;                                         \
            bl[nx] = *(const half8*)(bn + 16);                                  \
            acc[nt] = __builtin_amdgcn_mfma_f32_32x32x16_f16(ah, bh[cu], acc[nt], 0, 0, 0); \
            acc[nt] = __builtin_amdgcn_mfma_f32_32x32x16_f16(al, bh[cu], acc[nt], 0, 0, 0); \
            acc[nt] = __builtin_amdgcn_mfma_f32_32x32x16_f16(ah, bl[cu], acc[nt], 0, 0, 0); \
        }                                                                       \
    }

#pragma unroll 1
    for (int s = 0; s < NSB; ++s) {
        __syncthreads();               // stage(slice s) landed; buf^1 readers done
        const int abuf = (s & 1) * 32768;
        const int nbuf = abuf ^ 32768;
        if (s + 1 < NSB) {             // issue next slice into nbuf (in flight
            const float* g = gsrc0 + (s + 1) * 128;   //  across whole superblock)
#pragma unroll
            for (int i = 0; i < 4; ++i)
                GLL16(g + 32 * i, smem + nbuf + tid * 16 + i * 8192);
        }
        COMPUTE_KK(0)
        COMPUTE_KK(1)
        COMPUTE_KK(2)
        COMPUTE_KK(3)
        COMPUTE_KK(4)
        COMPUTE_KK(5)
        COMPUTE_KK(6)
        COMPUTE_KK(7)
    }

    // ---- epilogue: two 32-row phases; acc -> u_lds fp32, then routing ----
    // C/D layout 32x32: col = ln, row = (reg&3) + 8*(reg>>2) + 4*q
    const int dgrp = lane & 3;
#pragma unroll
    for (int p = 0; p < 2; ++p) {
        __syncthreads();               // K-loop / previous-phase LDS reads done
        if (mf == p) {                 // 4 waves with this m-half write 32x512
#pragma unroll
            for (int nt = 0; nt < 4; ++nt)
#pragma unroll
                for (int reg = 0; reg < 16; ++reg)
                    u_lds[(reg & 3) + 8 * (reg >> 2) + 4 * q][C0 + nt * 32 + ln] = acc[nt][reg];
        }
        __syncthreads();
#pragma unroll 1
        for (int ri = 0; ri < 4; ++ri) {
            const int rl = w * 4 + ri;               // local row 0..31
            const floatx4 ua = *(const floatx4*)&u_lds[rl][lane * 8];
            const floatx4 ub = *(const floatx4*)&u_lds[rl][lane * 8 + 4];
            const float u8[8] = {ua[0], ua[1], ua[2], ua[3],
                                 ub[0], ub[1], ub[2], ub[3]};
            float b_own = 0.f;
            float v[8];
#pragma unroll
            for (int it = 0; it < 3; ++it) {
                float c_own;
                if (it == 0) {
                    c_own = 1.0f / 16.0f;            // softmax of zeros
                } else {
                    const float m = cap_max(b_own);
                    const float e = __expf(b_own - m);
                    const float ssum = cap_sum(e);
                    c_own = e / ssum;
                }
                float s8[8];
#pragma unroll
                for (int j = 0; j < 8; ++j) s8[j] = c_own * u8[j];
#pragma unroll
                for (int j = 0; j < 8; ++j) s8[j] += dpp_mov<ROR4>(s8[j]);
#pragma unroll
                for (int j = 0; j < 8; ++j) s8[j] += dpp_mov<ROR8>(s8[j]);
#pragma unroll
                for (int j = 0; j < 8; ++j) s8[j] += swz_xor<16>(s8[j]);
#pragma unroll
                for (int j = 0; j < 8; ++j) s8[j] += __shfl_xor(s8[j], 32);
                float nrm = 0.f;
#pragma unroll
                for (int j = 0; j < 8; ++j) nrm = fmaf(s8[j], s8[j], nrm);
                nrm = dg_sum(nrm);
                const float scale = nrm / ((1.f + nrm) * (sqrtf(nrm) + EPS_F));
#pragma unroll
                for (int j = 0; j < 8; ++j) v[j] = scale * s8[j];
                if (it < 2) {
                    float dot = 0.f;
#pragma unroll
                    for (int j = 0; j < 8; ++j) dot = fmaf(u8[j], v[j], dot);
                    dot = dg_sum(dot);
                    b_own += dot;
                }
            }
            if (lane < 4) {
                float* o = out + (size_t)(rowBlk + p * 32 + rl) * OUT_DIM + dgrp * 8;
                floatx4 o0 = {v[0], v[1], v[2], v[3]};
                floatx4 o1 = {v[4], v[5], v[6], v[7]};
                __builtin_nontemporal_store(o0, (floatx4*)o);
                __builtin_nontemporal_store(o1, (floatx4*)(o + 4));
            }
        }
    }
}

extern "C" void kernel_launch(void* const* d_in, const int* in_sizes, int n_in,
                              void* d_out, int out_size, void* d_ws, size_t ws_size,
                              hipStream_t stream) {
    const float* x = (const float*)d_in[0];   // [32768, 512]
    const float* W = (const float*)d_in[1];   // [512, 512]
    float* out = (float*)d_out;               // [32768, 32]
    _Float16* Whl = (_Float16*)d_ws;          // [32][512][2][16] f16 tiled, 1 MB

    prep_w<<<dim3(16, 16), dim3(32, 8), 0, stream>>>(W, Whl);
    capsule_mfma<<<dim3(BATCH / 64), dim3(512), 0, stream>>>(x, Whl, out);
}

// Round 3
// 158.472 us; speedup vs baseline: 1.0560x; 1.0560x over previous
//
#include <hip/hip_runtime.h>
#include <math.h>

// CapsuleLayer: u = x@W via split-precision f16 MFMA (xh@Wh + xl@Wh + xh@Wl),
// 32x32x16. R13: m201-style per-kt PHASE schedule (R11 prefetch-depth null,
// R12 occupancy null => convoy of small stalls; the proven fix is the 8-phase
// barrier rhythm + counted waits + setprio, 62% MfmaUtil precedent):
//  - Block 512 thr (8 waves), tile 128 rows x 512 cols, grid 256 = 1 block/CU.
//  - Per kt: {window: issue B(kt+1) ring loads + staging slot + ds_read A(kt)}
//    -> raw s_barrier (NO vmcnt drain: loads stay in flight across) ->
//    setprio(1) 24 MFMA setprio(0) -> raw s_barrier. Compiler emits counted
//    vmcnt/lgkmcnt for the register deps (never drain-0 inside superblock).
//  - B ring parity compile-time: kt&1 == kk&1 (KPS=4) -> static bh0/bh1 sets.
//  - Staging: sv loads in window kk0, cvt+ds_write in windows kk2/kk3
//    (2-phase ~3600cy HBM-latency cover); __syncthreads only at superblock
//    boundaries (8 total) for LDS write->read safety.
// Proven invariants: R10 A-swizzle formulas verbatim (rows extended to 128),
// never runtime-index acc[]/ring (R6), lane-bit-5 cross only via bpermute
// (R5), C/D layout row=(reg&3)+8*(reg>>2)+4*q col=ln, routing math identical.
//
// x: [32768,512] fp32  W: [512,512] fp32  v: [32768,32] fp32
// prep_w: W[k][n] -> Whl tiled [kt][n][{h,l}][k%16] f16 in d_ws (1 MB).

#define BATCH   32768
#define KDIM    512
#define NDIM    512
#define OUT_DIM 32
#define EPS_F   1e-8f
#define NKT     32            // K tiles of 16
#define KPS     4             // kt per superblock
#define NSB     8             // superblocks
#define ROWS    128           // rows per block

typedef _Float16 half8  __attribute__((ext_vector_type(8)));
typedef _Float16 half4t __attribute__((ext_vector_type(4)));
typedef float   floatx4 __attribute__((ext_vector_type(4)));
typedef float  floatx16 __attribute__((ext_vector_type(16)));

// ---- cross-lane helpers (R7, proven) ----
template <int CTRL>
__device__ __forceinline__ float dpp_mov(float x) {
    return __int_as_float(__builtin_amdgcn_mov_dpp(__float_as_int(x), CTRL, 0xF, 0xF, true));
}
template <int XMASK>   // XMASK <= 31: ds_swizzle BitMode xor (within 32-lane group)
__device__ __forceinline__ float swz_xor(float x) {
    return __int_as_float(__builtin_amdgcn_ds_swizzle(__float_as_int(x), (XMASK << 10) | 31));
}
#define ROR4  0x124
#define ROR8  0x128
#define QXOR1 0xB1
#define QXOR2 0x4E

__device__ __forceinline__ float cap_sum(float x) {
    x += dpp_mov<ROR4>(x);
    x += dpp_mov<ROR8>(x);
    x += swz_xor<16>(x);
    x += __shfl_xor(x, 32);          // lane bit 5: bpermute only
    return x;
}
__device__ __forceinline__ float cap_max(float x) {
    x = fmaxf(x, dpp_mov<ROR4>(x));
    x = fmaxf(x, dpp_mov<ROR8>(x));
    x = fmaxf(x, swz_xor<16>(x));
    x = fmaxf(x, __shfl_xor(x, 32));
    return x;
}
__device__ __forceinline__ float dg_sum(float x) {
    x += dpp_mov<QXOR1>(x);
    x += dpp_mov<QXOR2>(x);
    return x;
}

// ---- prep: W[k][n] fp32 -> Whl [kt][n][{h(16B),l(16B)} per q] f16 ----
// Layout in halfs: off = kt*16384 + n*32 + (k&15); h at off, l at off+16.
__global__ void prep_w(const float* __restrict__ W, _Float16* __restrict__ Whl) {
    __shared__ float tile[32][33];
    const int tx = threadIdx.x, ty = threadIdx.y;      // block (32, 8)
    const int n0 = blockIdx.x * 32, k0 = blockIdx.y * 32;
#pragma unroll
    for (int i = 0; i < 4; ++i)
        tile[ty + 8 * i][tx] = W[(size_t)(k0 + ty + 8 * i) * NDIM + n0 + tx];
    __syncthreads();
#pragma unroll
    for (int i = 0; i < 4; ++i) {
        const int k = k0 + tx, n = n0 + ty + 8 * i;
        const float v = tile[tx][ty + 8 * i];          // = W[k][n]
        const _Float16 h = (_Float16)v;
        const _Float16 l = (_Float16)(v - (float)h);
        const size_t off = (size_t)(k >> 4) * (NDIM * 32) + (size_t)n * 32 + (k & 15);
        Whl[off]      = h;
        Whl[off + 16] = l;
    }
}

__global__ __launch_bounds__(512, 2)
void capsule_mfma(const float* __restrict__ x, const _Float16* __restrict__ Whl,
                  float* __restrict__ out) {
    // A f16 h/l dbuf: [2][kt'(4)][row(128)][64B] = 2x32KB = 64 KB,
    // unioned with u_lds[32][520] fp32 (66.56 KB).
    __shared__ __align__(16) char smem[66560];
    float (*u_lds)[520] = (float (*)[520])smem;

    const int tid  = threadIdx.x;
    const int w    = tid >> 6;          // wave 0..7
    const int lane = tid & 63;
    const int ln = lane & 31, q = lane >> 5;
    const int rowBlk = blockIdx.x * ROWS;
    const int rb = (w >> 2) * 64;       // wave row base (0 or 64)
    const int C0 = (w & 3) * 128;       // col strip

    floatx16 acc[2][4];
#pragma unroll
    for (int mf = 0; mf < 2; ++mf)
#pragma unroll
        for (int nt = 0; nt < 4; ++nt)
#pragma unroll
            for (int i = 0; i < 16; ++i) acc[mf][nt][i] = 0.f;

    // ---- A staging map: thread t -> (row t>>2, quarter t&3); i loop = kt' 0..3
    const int srow = tid >> 2;           // 0..127
    const int skq  = tid & 3;
    const int ssw  = (srow >> 1) & 3;
    const float* aga = x + (size_t)(rowBlk + srow) * KDIM + skq * 4;
    const int woffs = srow * 64 + (((skq >> 1) ^ ssw) * 16) + (skq & 1) * 8;
    // l-chunk offset = woffs ^ 32; kt' stride 8192 B

    // ---- A frag read offsets: rows rb+ln (m0) and rb+32+ln (m1 = +2048 B)
    const int r0 = rb + ln;
    const int hoff0 = r0 * 64 + ((q ^ ((r0 >> 1) & 3)) * 16);

    // ---- B lane offset (halfs) within (kt,nt) block of interleaved Whl ----
    const int lane_off = (C0 + ln) * 32 + q * 8;   // + nt*1024 + kt*16384

    // ---- prologue: B set0 = kt 0; stage slice 0 -> buf0 ----
    half8 bh0[4], bl0[4], bh1[4], bl1[4];
#pragma unroll
    for (int nt = 0; nt < 4; ++nt) {
        const _Float16* bp = Whl + nt * 1024 + lane_off;
        bh0[nt] = *(const half8*)bp;
        bl0[nt] = *(const half8*)(bp + 16);
    }
    {
        floatx4 s0[4];
#pragma unroll
        for (int i = 0; i < 4; ++i)
            s0[i] = *(const floatx4*)(aga + (size_t)i * 16);
#pragma unroll
        for (int i = 0; i < 4; ++i) {
            half4t h4, l4;
#pragma unroll
            for (int j = 0; j < 4; ++j) {
                h4[j] = (_Float16)s0[i][j];
                l4[j] = (_Float16)(s0[i][j] - (float)h4[j]);
            }
            *(half4t*)(smem + woffs + i * 8192)        = h4;
            *(half4t*)(smem + (woffs ^ 32) + i * 8192) = l4;
        }
    }

#define MFMA24(AH0, AL0, AH1, AL1, BH, BL)                                      \
    _Pragma("unroll")                                                           \
    for (int nt = 0; nt < 4; ++nt) {                                            \
        acc[0][nt] = __builtin_amdgcn_mfma_f32_32x32x16_f16(AH0, BH[nt], acc[0][nt], 0, 0, 0); \
        acc[0][nt] = __builtin_amdgcn_mfma_f32_32x32x16_f16(AL0, BH[nt], acc[0][nt], 0, 0, 0); \
        acc[1][nt] = __builtin_amdgcn_mfma_f32_32x32x16_f16(AH1, BH[nt], acc[1][nt], 0, 0, 0); \
        acc[1][nt] = __builtin_amdgcn_mfma_f32_32x32x16_f16(AL1, BH[nt], acc[1][nt], 0, 0, 0); \
        acc[0][nt] = __builtin_amdgcn_mfma_f32_32x32x16_f16(AH0, BL[nt], acc[0][nt], 0, 0, 0); \
        acc[1][nt] = __builtin_amdgcn_mfma_f32_32x32x16_f16(AH1, BL[nt], acc[1][nt], 0, 0, 0); \
    }

// Window: prefetch B(kt+1) into the NX set, read A(kt) frags, run the staging
// slot; then barrier -> prioritized MFMA burst on the CU set -> barrier.
// Raw barriers: no counter drain, loads span phases (T4).
#define PHASE(kk, BHC, BLC, BHN, BLN, STG)                                      \
    {                                                                           \
        const int kt = s * KPS + (kk);                                          \
        const int ktn = (kt + 1 < NKT) ? kt + 1 : kt;                           \
        const _Float16* bkt = Whl + (size_t)ktn * 16384 + lane_off;             \
        _Pragma("unroll")                                                       \
        for (int nt = 0; nt < 4; ++nt) {                                        \
            BHN[nt] = *(const half8*)(bkt + nt * 1024);                         \
            BLN[nt] = *(const half8*)(bkt + nt * 1024 + 16);                    \
        }                                                                       \
        const char* ab = smem + abuf + (kk) * 8192;                             \
        const half8 ah0 = *(const half8*)(ab + hoff0);                          \
        const half8 al0 = *(const half8*)(ab + (hoff0 ^ 32));                   \
        const half8 ah1 = *(const half8*)(ab + hoff0 + 2048);                   \
        const half8 al1 = *(const half8*)(ab + ((hoff0 + 2048) ^ 32));          \
        STG;                                                                    \
        __builtin_amdgcn_s_barrier();                                           \
        __builtin_amdgcn_s_setprio(1);                                          \
        MFMA24(ah0, al0, ah1, al1, BHC, BLC)                                    \
        __builtin_amdgcn_s_setprio(0);                                          \
        __builtin_amdgcn_s_barrier();                                           \
    }

#define STG_NONE ((void)0)
#define STG_LOAD                                                                \
    if (s + 1 < NSB) {                                                          \
        _Pragma("unroll")                                                       \
        for (int i = 0; i < 4; ++i)                                             \
            sv[i] = *(const floatx4*)(aga + (size_t)((s + 1) * 4 + i) * 16);    \
    }
#define STG_CW(i0)                                                              \
    if (s + 1 < NSB) {                                                          \
        _Pragma("unroll")                                                       \
        for (int i = (i0); i < (i0) + 2; ++i) {                                 \
            half4t h4, l4;                                                      \
            _Pragma("unroll")                                                   \
            for (int j = 0; j < 4; ++j) {                                       \
                h4[j] = (_Float16)sv[i][j];                                     \
                l4[j] = (_Float16)(sv[i][j] - (float)h4[j]);                    \
            }                                                                   \
            *(half4t*)(smem + nbuf + woffs + i * 8192)        = h4;             \
            *(half4t*)(smem + nbuf + (woffs ^ 32) + i * 8192) = l4;             \
        }                                                                       \
    }

#pragma unroll 1
    for (int s = 0; s < NSB; ++s) {
        __syncthreads();               // slice s visible; buf^1 readers done
        const int abuf = (s & 1) * 32768;
        const int nbuf = abuf ^ 32768;
        floatx4 sv[4];
        PHASE(0, bh0, bl0, bh1, bl1, STG_LOAD)   // kt even: consume set0
        PHASE(1, bh1, bl1, bh0, bl0, STG_NONE)   // kt odd:  consume set1
        PHASE(2, bh0, bl0, bh1, bl1, STG_CW(0))
        PHASE(3, bh1, bl1, bh0, bl0, STG_CW(2))
    }

    // ---- epilogue: four 32-row phases; acc -> u_lds fp32, then routing ----
    // C/D layout 32x32: col = ln, row = (reg&3) + 8*(reg>>2) + 4*q
    const int dgrp = lane & 3;
#pragma unroll
    for (int p = 0; p < 4; ++p) {
        __syncthreads();               // K-loop / previous-phase LDS reads done
        if ((w >> 2) == (p >> 1)) {    // 4 waves own block rows p*32..+31
#pragma unroll
            for (int nt = 0; nt < 4; ++nt)
#pragma unroll
                for (int reg = 0; reg < 16; ++reg)
                    u_lds[(reg & 3) + 8 * (reg >> 2) + 4 * q][C0 + nt * 32 + ln] = acc[p & 1][nt][reg];
        }
        __syncthreads();
#pragma unroll 1
        for (int ri = 0; ri < 4; ++ri) {
            const int rl = w * 4 + ri;               // local row 0..31
            const floatx4 ua = *(const floatx4*)&u_lds[rl][lane * 8];
            const floatx4 ub = *(const floatx4*)&u_lds[rl][lane * 8 + 4];
            const float u8[8] = {ua[0], ua[1], ua[2], ua[3],
                                 ub[0], ub[1], ub[2], ub[3]};
            float b_own = 0.f;
            float v[8];
#pragma unroll
            for (int it = 0; it < 3; ++it) {
                float c_own;
                if (it == 0) {
                    c_own = 1.0f / 16.0f;            // softmax of zeros
                } else {
                    const float m = cap_max(b_own);
                    const float e = __expf(b_own - m);
                    const float ssum = cap_sum(e);
                    c_own = e / ssum;
                }
                float s8[8];
#pragma unroll
                for (int j = 0; j < 8; ++j) s8[j] = c_own * u8[j];
#pragma unroll
                for (int j = 0; j < 8; ++j) s8[j] += dpp_mov<ROR4>(s8[j]);
#pragma unroll
                for (int j = 0; j < 8; ++j) s8[j] += dpp_mov<ROR8>(s8[j]);
#pragma unroll
                for (int j = 0; j < 8; ++j) s8[j] += swz_xor<16>(s8[j]);
#pragma unroll
                for (int j = 0; j < 8; ++j) s8[j] += __shfl_xor(s8[j], 32);
                float nrm = 0.f;
#pragma unroll
                for (int j = 0; j < 8; ++j) nrm = fmaf(s8[j], s8[j], nrm);
                nrm = dg_sum(nrm);
                const float scale = nrm / ((1.f + nrm) * (sqrtf(nrm) + EPS_F));
#pragma unroll
                for (int j = 0; j < 8; ++j) v[j] = scale * s8[j];
                if (it < 2) {
                    float dot = 0.f;
#pragma unroll
                    for (int j = 0; j < 8; ++j) dot = fmaf(u8[j], v[j], dot);
                    dot = dg_sum(dot);
                    b_own += dot;
                }
            }
            if (lane < 4) {
                float* o = out + (size_t)(rowBlk + p * 32 + rl) * OUT_DIM + dgrp * 8;
                floatx4 o0 = {v[0], v[1], v[2], v[3]};
                floatx4 o1 = {v[4], v[5], v[6], v[7]};
                __builtin_nontemporal_store(o0, (floatx4*)o);
                __builtin_nontemporal_store(o1, (floatx4*)(o + 4));
            }
        }
    }
}

extern "C" void kernel_launch(void* const* d_in, const int* in_sizes, int n_in,
                              void* d_out, int out_size, void* d_ws, size_t ws_size,
                              hipStream_t stream) {
    const float* x = (const float*)d_in[0];   // [32768, 512]
    const float* W = (const float*)d_in[1];   // [512, 512]
    float* out = (float*)d_out;               // [32768, 32]
    _Float16* Whl = (_Float16*)d_ws;          // [32][512][2][16] f16 tiled, 1 MB

    prep_w<<<dim3(16, 16), dim3(32, 8), 0, stream>>>(W, Whl);
    capsule_mfma<<<dim3(BATCH / ROWS), dim3(512), 0, stream>>>(x, Whl, out);
}

// Round 4
// 154.237 us; speedup vs baseline: 1.0850x; 1.0275x over previous
//
#include <hip/hip_runtime.h>
#include <math.h>

// CapsuleLayer: u = x@W via split-precision f16 MFMA (xh@Wh + xl@Wh + xh@Wl),
// 32x32x16. R14: R10 base restored VERBATIM (proven 84-88us; R11 prefetch
// null, R12 occupancy negative, R13 phase-barriers negative -> K-loop
// structure levers exhausted, MfmaUtil*dur==20.6us const in all).
// SINGLE change vs R10: epilogue routes rows in PAIRS -- two independent
// per-row chains written interleaved, so row B's ops fill row A's serial
// latencies (softmax cap-reduce = 2x ~120cy LDS-op latency + exp + s-reduce
// + sqrt/div + dot chain ~ 2.2k cyc/row, est 12-15us of the 88 at 2 w/SIMD).
// Per-row FP order byte-identical to R10 => absmax unchanged.
// Proven invariants: never runtime-index acc[] (R6 spill); lane-bit-5 cross
// only via bpermute (R5); C/D layout row=(reg&3)+8*(reg>>2)+4*q, col=ln.
//
// x: [32768,512] fp32  W: [512,512] fp32  v: [32768,32] fp32
// prep_w: W[k][n] -> Wh/Wl tiled [kt][n][k%16] f16 in d_ws (1 MB).
// Main: block = 256 thr (4 waves), tile 64 rows x 512 cols, grid 512
// (2 blocks/CU: LDS 66.56KB, VGPR<=256 via __launch_bounds__(256,2)).
// Wave w: all 64 rows (2 m-frags) x cols w*128..+127 (4 n-tiles).

#define BATCH   32768
#define KDIM    512
#define NDIM    512
#define OUT_DIM 32
#define EPS_F   1e-8f
#define NKT     32            // K tiles of 16
#define KPS     8             // kt per superblock
#define NSB     4             // superblocks

typedef _Float16 half8  __attribute__((ext_vector_type(8)));
typedef _Float16 half4t __attribute__((ext_vector_type(4)));
typedef float   floatx4 __attribute__((ext_vector_type(4)));
typedef float  floatx16 __attribute__((ext_vector_type(16)));

// ---- cross-lane helpers (R7, proven) ----
template <int CTRL>
__device__ __forceinline__ float dpp_mov(float x) {
    return __int_as_float(__builtin_amdgcn_mov_dpp(__float_as_int(x), CTRL, 0xF, 0xF, true));
}
template <int XMASK>   // XMASK <= 31: ds_swizzle BitMode xor (within 32-lane group)
__device__ __forceinline__ float swz_xor(float x) {
    return __int_as_float(__builtin_amdgcn_ds_swizzle(__float_as_int(x), (XMASK << 10) | 31));
}
#define ROR4  0x124
#define ROR8  0x128
#define QXOR1 0xB1
#define QXOR2 0x4E

__device__ __forceinline__ float cap_sum(float x) {
    x += dpp_mov<ROR4>(x);
    x += dpp_mov<ROR8>(x);
    x += swz_xor<16>(x);
    x += __shfl_xor(x, 32);          // lane bit 5: bpermute only
    return x;
}
__device__ __forceinline__ float cap_max(float x) {
    x = fmaxf(x, dpp_mov<ROR4>(x));
    x = fmaxf(x, dpp_mov<ROR8>(x));
    x = fmaxf(x, swz_xor<16>(x));
    x = fmaxf(x, __shfl_xor(x, 32));
    return x;
}
__device__ __forceinline__ float dg_sum(float x) {
    x += dpp_mov<QXOR1>(x);
    x += dpp_mov<QXOR2>(x);
    return x;
}

// ---- prep: W[k][n] fp32 -> Wh/Wl [kt][n][k%16] f16 hi/lo split ----
__global__ void prep_w(const float* __restrict__ W, _Float16* __restrict__ Wh,
                       _Float16* __restrict__ Wl) {
    __shared__ float tile[32][33];
    const int tx = threadIdx.x, ty = threadIdx.y;      // block (32, 8)
    const int n0 = blockIdx.x * 32, k0 = blockIdx.y * 32;
#pragma unroll
    for (int i = 0; i < 4; ++i)
        tile[ty + 8 * i][tx] = W[(size_t)(k0 + ty + 8 * i) * NDIM + n0 + tx];
    __syncthreads();
#pragma unroll
    for (int i = 0; i < 4; ++i) {
        const int k = k0 + tx, n = n0 + ty + 8 * i;
        const float v = tile[tx][ty + 8 * i];          // = W[k][n]
        const _Float16 h = (_Float16)v;
        const _Float16 l = (_Float16)(v - (float)h);
        const size_t off = (size_t)(k >> 4) * (NDIM * 16) + (size_t)n * 16 + (k & 15);
        Wh[off] = h;
        Wl[off] = l;
    }
}

__global__ __launch_bounds__(256, 2)
void capsule_mfma(const float* __restrict__ x, const _Float16* __restrict__ Wh,
                  const _Float16* __restrict__ Wl, float* __restrict__ out) {
    // As[buf(2)][kt'(8)][row 64][64B] = 64 KB, unioned with u_lds[32][520] (66.56 KB)
    __shared__ __align__(16) char smem[66560];
    float (*u_lds)[520] = (float (*)[520])smem;

    const int tid  = threadIdx.x;
    const int w    = tid >> 6;          // wave 0..3
    const int lane = tid & 63;
    const int ln = lane & 31, q = lane >> 5;
    const int rowBlk = blockIdx.x * 64;
    const int C0 = w * 128;

    floatx16 acc[2][4];
#pragma unroll
    for (int mf = 0; mf < 2; ++mf)
#pragma unroll
        for (int nt = 0; nt < 4; ++nt)
#pragma unroll
            for (int i = 0; i < 16; ++i) acc[mf][nt][i] = 0.f;

    // ---- A staging mapping: thread -> (row srow0+8i, kt' skt, quarter skq) ----
    const int srow0 = tid >> 5;          // 0..7
    const int sf    = tid & 31;
    const int skt   = sf >> 2;           // 0..7
    const int skq   = sf & 3;
    const float* aga = x + (size_t)(rowBlk + srow0) * KDIM + skt * 16 + skq * 4;
    const int ssw = (srow0 >> 1) & 3;    // i-invariant ((+8i)>>1 adds 4, &3 unchanged)
    const int woffh = skt * 4096 + srow0 * 64 + (((skq >> 1) ^ ssw) * 16) + (skq & 1) * 8;
    // l-chunk offset = woffh ^ 32

    // ---- A frag read offsets: ar = mf*32+ln; hoff1 = hoff0 + 2048; loff = hoff^32
    const int hoff0 = ln * 64 + ((q ^ ((ln >> 1) & 3)) * 16);

    // ---- B lane offset (halfs): frag (kt,nt) at Wh + kt*8192 + nt*512 + boff
    const int boff = (C0 + ln) * 16 + q * 8;

    // ---- prologue: stage slice 0 -> buf0; load B(0,0) ----
    {
        floatx4 s0[8];
#pragma unroll
        for (int i = 0; i < 8; ++i)
            s0[i] = *(const floatx4*)(aga + (size_t)(8 * i) * KDIM);
#pragma unroll
        for (int i = 0; i < 8; ++i) {
            half4t h4, l4;
#pragma unroll
            for (int j = 0; j < 4; ++j) {
                h4[j] = (_Float16)s0[i][j];
                l4[j] = (_Float16)(s0[i][j] - (float)h4[j]);
            }
            *(half4t*)(smem + woffh + i * 512)        = h4;
            *(half4t*)(smem + (woffh ^ 32) + i * 512) = l4;
        }
    }
    half8 bh[2], bl[2];
    bh[0] = *(const half8*)(Wh + boff);
    bl[0] = *(const half8*)(Wl + boff);

#define COMPUTE_KK(kk)                                                          \
    {                                                                           \
        const int kt = s * KPS + (kk);                                          \
        const char* ab = smem + abuf + (kk) * 4096;                             \
        const half8 ah0 = *(const half8*)(ab + hoff0);                          \
        const half8 al0 = *(const half8*)(ab + (hoff0 ^ 32));                   \
        const half8 ah1 = *(const half8*)(ab + hoff0 + 2048);                   \
        const half8 al1 = *(const half8*)(ab + ((hoff0 + 2048) ^ 32));          \
        _Pragma("unroll")                                                       \
        for (int nt = 0; nt < 4; ++nt) {                                        \
            const int cu = nt & 1, nx = cu ^ 1;                                 \
            const int kn = (nt < 3) ? kt : ((kt + 1 < NKT) ? kt + 1 : kt);      \
            const int nn = (nt < 3) ? nt + 1 : 0;                               \
            bh[nx] = *(const half8*)(Wh + (size_t)kn * 8192 + nn * 512 + boff); \
            bl[nx] = *(const half8*)(Wl + (size_t)kn * 8192 + nn * 512 + boff); \
            acc[0][nt] = __builtin_amdgcn_mfma_f32_32x32x16_f16(ah0, bh[cu], acc[0][nt], 0, 0, 0); \
            acc[0][nt] = __builtin_amdgcn_mfma_f32_32x32x16_f16(al0, bh[cu], acc[0][nt], 0, 0, 0); \
            acc[0][nt] = __builtin_amdgcn_mfma_f32_32x32x16_f16(ah0, bl[cu], acc[0][nt], 0, 0, 0); \
            acc[1][nt] = __builtin_amdgcn_mfma_f32_32x32x16_f16(ah1, bh[cu], acc[1][nt], 0, 0, 0); \
            acc[1][nt] = __builtin_amdgcn_mfma_f32_32x32x16_f16(al1, bh[cu], acc[1][nt], 0, 0, 0); \
            acc[1][nt] = __builtin_amdgcn_mfma_f32_32x32x16_f16(ah1, bl[cu], acc[1][nt], 0, 0, 0); \
        }                                                                       \
    }

#define STAGE_HALF(h0)                                                          \
    {                                                                           \
        half4t h4, l4;                                                          \
        _Pragma("unroll")                                                       \
        for (int i = 0; i < 4; ++i) {                                           \
            _Pragma("unroll")                                                   \
            for (int j = 0; j < 4; ++j) {                                       \
                h4[j] = (_Float16)sv[i][j];                                     \
                l4[j] = (_Float16)(sv[i][j] - (float)h4[j]);                    \
            }                                                                   \
            *(half4t*)(smem + nbuf + woffh + ((h0) + i) * 512)        = h4;     \
            *(half4t*)(smem + nbuf + ((woffh ^ 32)) + ((h0) + i) * 512) = l4;   \
        }                                                                       \
    }

#pragma unroll 1
    for (int s = 0; s < NSB; ++s) {
        __syncthreads();               // stage(slice s) visible; buf^1 readers done
        const int abuf = (s & 1) * 32768;
        const int nbuf = abuf ^ 32768;
        floatx4 sv[4];
        if (s + 1 < NSB) {             // load half 0 of slice s+1 (rows +0..+24)
#pragma unroll
            for (int i = 0; i < 4; ++i)
                sv[i] = *(const floatx4*)(aga + (size_t)(s + 1) * 128 + (size_t)(8 * i) * KDIM);
        }
        COMPUTE_KK(0)
        COMPUTE_KK(1)
        if (s + 1 < NSB) STAGE_HALF(0)
        if (s + 1 < NSB) {             // load half 1 (rows +32..+56)
#pragma unroll
            for (int i = 0; i < 4; ++i)
                sv[i] = *(const floatx4*)(aga + (size_t)(s + 1) * 128 + (size_t)(8 * (i + 4)) * KDIM);
        }
        COMPUTE_KK(2)
        COMPUTE_KK(3)
        COMPUTE_KK(4)
        COMPUTE_KK(5)
        if (s + 1 < NSB) STAGE_HALF(4)
        COMPUTE_KK(6)
        COMPUTE_KK(7)
    }

    // ---- epilogue: two 32-row phases; acc -> u_lds fp32, then PAIRED routing ----
    // C/D layout 32x32: col = ln, row = (reg&3) + 8*(reg>>2) + 4*q
    const int dgrp = lane & 3;
#pragma unroll
    for (int p = 0; p < 2; ++p) {
        __syncthreads();               // K-loop / previous-phase LDS reads done
        {
            const int mf = p;          // compile-time (p unrolled) — R6 rule
#pragma unroll
            for (int nt = 0; nt < 4; ++nt)
#pragma unroll
                for (int reg = 0; reg < 16; ++reg)
                    u_lds[(reg & 3) + 8 * (reg >> 2) + 4 * q][C0 + nt * 32 + ln] = acc[mf][nt][reg];
        }
        __syncthreads();
        // R14: rows processed in pairs — two independent chains interleaved so
        // row B's ops cover row A's LDS-op/transcendental latencies.
#pragma unroll 1
        for (int pi = 0; pi < 4; ++pi) {
            const int rl0 = w * 8 + 2 * pi;          // local rows rl0, rl0+1
            const floatx4 uaA = *(const floatx4*)&u_lds[rl0][lane * 8];
            const floatx4 ubA = *(const floatx4*)&u_lds[rl0][lane * 8 + 4];
            const floatx4 uaB = *(const floatx4*)&u_lds[rl0 + 1][lane * 8];
            const floatx4 ubB = *(const floatx4*)&u_lds[rl0 + 1][lane * 8 + 4];
            const float uA[8] = {uaA[0], uaA[1], uaA[2], uaA[3],
                                 ubA[0], ubA[1], ubA[2], ubA[3]};
            const float uB[8] = {uaB[0], uaB[1], uaB[2], uaB[3],
                                 ubB[0], ubB[1], ubB[2], ubB[3]};
            float bA = 0.f, bB = 0.f;
            float vA[8], vB[8];
#pragma unroll
            for (int it = 0; it < 3; ++it) {
                float cA, cB;
                if (it == 0) {
                    cA = 1.0f / 16.0f;               // softmax of zeros
                    cB = 1.0f / 16.0f;
                } else {
                    const float mA = cap_max(bA);
                    const float mB = cap_max(bB);
                    const float eA = __expf(bA - mA);
                    const float eB = __expf(bB - mB);
                    const float sAs = cap_sum(eA);
                    const float sBs = cap_sum(eB);
                    cA = eA / sAs;
                    cB = eB / sBs;
                }
                float s8A[8], s8B[8];
#pragma unroll
                for (int j = 0; j < 8; ++j) { s8A[j] = cA * uA[j]; s8B[j] = cB * uB[j]; }
#pragma unroll
                for (int j = 0; j < 8; ++j) { s8A[j] += dpp_mov<ROR4>(s8A[j]); s8B[j] += dpp_mov<ROR4>(s8B[j]); }
#pragma unroll
                for (int j = 0; j < 8; ++j) { s8A[j] += dpp_mov<ROR8>(s8A[j]); s8B[j] += dpp_mov<ROR8>(s8B[j]); }
#pragma unroll
                for (int j = 0; j < 8; ++j) { s8A[j] += swz_xor<16>(s8A[j]); s8B[j] += swz_xor<16>(s8B[j]); }
#pragma unroll
                for (int j = 0; j < 8; ++j) { s8A[j] += __shfl_xor(s8A[j], 32); s8B[j] += __shfl_xor(s8B[j], 32); }
                float nrmA = 0.f, nrmB = 0.f;
#pragma unroll
                for (int j = 0; j < 8; ++j) { nrmA = fmaf(s8A[j], s8A[j], nrmA); nrmB = fmaf(s8B[j], s8B[j], nrmB); }
                nrmA = dg_sum(nrmA);
                nrmB = dg_sum(nrmB);
                const float scaleA = nrmA / ((1.f + nrmA) * (sqrtf(nrmA) + EPS_F));
                const float scaleB = nrmB / ((1.f + nrmB) * (sqrtf(nrmB) + EPS_F));
#pragma unroll
                for (int j = 0; j < 8; ++j) { vA[j] = scaleA * s8A[j]; vB[j] = scaleB * s8B[j]; }
                if (it < 2) {
                    float dotA = 0.f, dotB = 0.f;
#pragma unroll
                    for (int j = 0; j < 8; ++j) { dotA = fmaf(uA[j], vA[j], dotA); dotB = fmaf(uB[j], vB[j], dotB); }
                    dotA = dg_sum(dotA);
                    dotB = dg_sum(dotB);
                    bA += dotA;
                    bB += dotB;
                }
            }
            if (lane < 4) {
                float4* o0 = (float4*)(out + (size_t)(rowBlk + p * 32 + rl0) * OUT_DIM
                                       + dgrp * 8);
                o0[0] = make_float4(vA[0], vA[1], vA[2], vA[3]);
                o0[1] = make_float4(vA[4], vA[5], vA[6], vA[7]);
                float4* o1 = (float4*)(out + (size_t)(rowBlk + p * 32 + rl0 + 1) * OUT_DIM
                                       + dgrp * 8);
                o1[0] = make_float4(vB[0], vB[1], vB[2], vB[3]);
                o1[1] = make_float4(vB[4], vB[5], vB[6], vB[7]);
            }
        }
    }
}

extern "C" void kernel_launch(void* const* d_in, const int* in_sizes, int n_in,
                              void* d_out, int out_size, void* d_ws, size_t ws_size,
                              hipStream_t stream) {
    const float* x = (const float*)d_in[0];   // [32768, 512]
    const float* W = (const float*)d_in[1];   // [512, 512]
    float* out = (float*)d_out;               // [32768, 32]
    _Float16* Wh = (_Float16*)d_ws;           // [32][512][16] f16 tiled
    _Float16* Wl = Wh + (size_t)NDIM * KDIM;

    prep_w<<<dim3(16, 16), dim3(32, 8), 0, stream>>>(W, Wh, Wl);
    capsule_mfma<<<dim3(BATCH / 64), dim3(256), 0, stream>>>(x, Wh, Wl, out);
}